// Round 16
// baseline (535.801 us; speedup 1.0000x reference)
//
#include <hip/hip_runtime.h>
#include <cstddef>
#include <cstdint>

// SNN: 4x (Linear + LIF). fp16 2-term exact splitting + fused in-LDS LIF
// (R14 base, passed absmax 0.0). R16: gemm_mainL K-loop uses the R12-PROVEN
// full-tile single-phase ledger: per tile {stage(t+1) 8 loads; vmcnt(8);
// barrier; 16 ds_reads + 64 MFMA cluster; barrier}. Half the barriers of
// R14, wait distance = 1 full tile (~1200 cyc). Prologue vmcnt(0); t=0
// wait is a no-op; tail dummy lands in the dead buffer. Per-acc MFMA order
// unchanged -> bit-identical numerics. gemm_corr / splits / seg_lif /
// epilogues verbatim R14.

#define BETA 0.95f

static constexpr int B_ = 128;
static constexpr int T_ = 64;
static constexpr int M_ = B_ * T_;       // 8192 rows
static constexpr int NOUT = 128;

typedef __bf16 bf16x8 __attribute__((ext_vector_type(8)));
typedef _Float16 f16x8 __attribute__((ext_vector_type(8)));
typedef float f32x4 __attribute__((ext_vector_type(4)));
typedef ushort u16x8 __attribute__((ext_vector_type(8)));

__device__ __forceinline__ ushort f32_bf16_rne(float f) {
  uint32_t u = __float_as_uint(f);
  uint32_t r = u + 0x7FFFu + ((u >> 16) & 1u);
  return (ushort)(r >> 16);
}
__device__ __forceinline__ float bf16_f32(ushort h) {
  return __uint_as_float(((uint32_t)h) << 16);
}
__device__ __forceinline__ ushort h2u(_Float16 h) {
  union { _Float16 h; ushort u; } v; v.h = h; return v.u;
}
__device__ __forceinline__ _Float16 u2h(ushort u) {
  union { ushort u; _Float16 h; } v; v.u = u; return v.h;
}

// ---------------------------------------------------------------------------
// fp32 -> 2 fp16 exact split (h + 2^-12 * l'), mode-1 swizzled positions.
// Subnormal-safe: |h|<2^-14 zeroed; value flows through l'.
// ---------------------------------------------------------------------------
__global__ __launch_bounds__(256) void split2_f16(
    const float* __restrict__ S, ushort* __restrict__ oh,
    ushort* __restrict__ ol, int K, int nslots)
{
  int g = blockIdx.x * 256 + threadIdx.x;
  if (g >= nslots) return;
  int spr = K >> 3;
  int row = g / spr;
  int sl = g - row * spr;
  int kb = sl >> 3;
  int slot = sl & 7;
  int pslot = (slot & 4) | ((slot & 3) ^ ((row >> 1) & 3));
  const float* src = S + (size_t)row * K + (kb << 6) + (slot << 3);
  size_t dst = (size_t)row * K + (kb << 6) + (pslot << 3);
  u16x8 vh, vl;
#pragma unroll
  for (int i = 0; i < 8; ++i) {
    float f = src[i];
    _Float16 h = (_Float16)f;
    float hf = (float)h;
    if (fabsf(hf) < 6.103515625e-05f) { h = (_Float16)0.0f; hf = 0.0f; }
    float l = (f - hf) * 4096.0f;
    vh[i] = h2u(h);
    vl[i] = h2u((_Float16)l);
  }
  *reinterpret_cast<u16x8*>(oh + dst) = vh;
  *reinterpret_cast<u16x8*>(ol + dst) = vl;
}

// ---------------------------------------------------------------------------
// fp32 -> 3 bf16 exact split, mode-0 swizzle (L3 operands only).
// ---------------------------------------------------------------------------
__global__ __launch_bounds__(256) void split3_swz(
    const float* __restrict__ S, ushort* __restrict__ o1,
    ushort* __restrict__ o2, ushort* __restrict__ o3,
    int K, int nslots)
{
  int g = blockIdx.x * 256 + threadIdx.x;
  if (g >= nslots) return;
  int spr = K >> 3;
  int row = g / spr;
  int sl = g - row * spr;
  int kb = sl >> 3;
  int slot = sl & 7;
  int pslot = slot ^ (row & 7);
  const float* src = S + (size_t)row * K + (kb << 6) + (slot << 3);
  size_t dst = (size_t)row * K + (kb << 6) + (pslot << 3);
  u16x8 v1, v2, v3;
#pragma unroll
  for (int i = 0; i < 8; ++i) {
    float f = src[i];
    ushort h1 = f32_bf16_rne(f);
    float r = f - bf16_f32(h1);
    ushort h2 = f32_bf16_rne(r);
    float r2 = r - bf16_f32(h2);
    ushort h3 = f32_bf16_rne(r2);
    v1[i] = h1; v2[i] = h2; v3[i] = h3;
  }
  *reinterpret_cast<u16x8*>(o1 + dst) = v1;
  *reinterpret_cast<u16x8*>(o2 + dst) = v2;
  *reinterpret_cast<u16x8*>(o3 + dst) = v3;
}

// ---------------------------------------------------------------------------
// gemm_corr: L0 corr pass (xl*wh), verbatim R14 (passed).
// ---------------------------------------------------------------------------
__global__ __launch_bounds__(512) void gemm_corr(
    const ushort* __restrict__ A, const ushort* __restrict__ Bh,
    int NT, int K, int N, ushort* __restrict__ curC)
{
  __shared__ __align__(16) ushort lds[49152];

  const int tid = threadIdx.x;
  const int lane = tid & 63;
  const int wid = tid >> 6;
  const int wm = wid >> 1;
  const int wn = wid & 1;
  const int lane15 = lane & 15;
  const int lhi = lane >> 4;
  const int sg2 = lhi ^ ((lane15 >> 1) & 3);

  int nwg = gridDim.x * gridDim.y;
  int bid = blockIdx.y * gridDim.x + blockIdx.x;
  int cpx = nwg >> 3;
  int sw = (bid & 7) * cpx + (bid >> 3);
  int bx = sw % gridDim.x, by = sw / gridDim.x;
  const int bm = by * 256, bn = bx * 128;

  const int sr2 = tid >> 2;
  const int sg = tid & 3;

  auto stage = [&](int t1, int h, int d) {
    const int k0 = t1 * 64 + h * 32;
#pragma unroll
    for (int l = 0; l < 2; ++l) {
      int row = sr2 + l * 128;
      __builtin_amdgcn_global_load_lds(
          (const __attribute__((address_space(1))) void*)(A + (size_t)(bm + row) * K + k0 + sg * 8),
          (__attribute__((address_space(3))) void*)(lds + d * 16384 + h * 8192 + row * 32 + sg * 8),
          16, 0, 0);
    }
    __builtin_amdgcn_global_load_lds(
        (const __attribute__((address_space(1))) void*)(Bh + (size_t)(bn + sr2) * K + k0 + sg * 8),
        (__attribute__((address_space(3))) void*)(lds + 32768 + (d * 2 + h) * 4096 + sr2 * 32 + sg * 8),
        16, 0, 0);
  };

  f32x4 accC[4][4];
#pragma unroll
  for (int i = 0; i < 4; ++i)
#pragma unroll
    for (int j = 0; j < 4; ++j)
      accC[i][j] = (f32x4){0.f, 0.f, 0.f, 0.f};

  stage(0, 0, 0);
  stage(0, 1, 0);
  asm volatile("s_waitcnt vmcnt(3)" ::: "memory");
  asm volatile("s_barrier" ::: "memory");

  for (int t = 0; t < NT; ++t) {
    const int d = t & 1;
#pragma unroll
    for (int h = 0; h < 2; ++h) {
      f16x8 af[4];
      const ushort* Ab = lds + (d * 2 + h) * 8192;
#pragma unroll
      for (int i = 0; i < 4; ++i)
        af[i] = *(const f16x8*)(Ab + (wm * 64 + i * 16 + lane15) * 32 + sg2 * 8);

      if (t < NT - 1) {
        stage(t + 1, h, d ^ 1);
        asm volatile("s_waitcnt vmcnt(3)" ::: "memory");
      } else if (h == 0) {
        asm volatile("s_waitcnt vmcnt(0)" ::: "memory");
      }
      asm volatile("s_barrier" ::: "memory");

      const ushort* Bb = lds + 32768 + (d * 2 + h) * 4096;
      f16x8 bf[4];
#pragma unroll
      for (int j = 0; j < 4; ++j)
        bf[j] = *(const f16x8*)(Bb + (wn * 64 + j * 16 + lane15) * 32 + sg2 * 8);
      __builtin_amdgcn_s_setprio(1);
#pragma unroll
      for (int i = 0; i < 4; ++i)
#pragma unroll
        for (int j = 0; j < 4; ++j)
          accC[i][j] = __builtin_amdgcn_mfma_f32_16x16x32_f16(af[i], bf[j], accC[i][j], 0, 0, 0);
      __builtin_amdgcn_s_setprio(0);
      asm volatile("s_barrier" ::: "memory");
    }
  }

#pragma unroll
  for (int i = 0; i < 4; ++i) {
    int r0 = bm + wm * 64 + i * 16 + lhi * 4;
#pragma unroll
    for (int j = 0; j < 4; ++j) {
      int col = bn + wn * 64 + j * 16 + lane15;
      f32x4 vc = accC[i][j];
#pragma unroll
      for (int r = 0; r < 4; ++r)
        curC[(size_t)(r0 + r) * N + col] = h2u((_Float16)vc[r]);
    }
  }
}

// ---------------------------------------------------------------------------
// gemm_mainL<HASC, FMT>: R12-proven single-phase ledger + R14 fused LIF.
// LDS: A [2 dbuf][2 half][256][32] f16 (64KB) + B [2 dbuf][2 half][2 seg]
// [128][32] (64KB) at 32768; epilogue reuses as [256][132] f32.
// Per tile t (d=t&1): stage full tile t+1 into d^1 (8 loads: 2A+2B per
// half); vmcnt(8) (drains tile t, staged one full tile earlier; no-op at
// t=0 where prologue confirmed tile 0); barrier; {per h: af[4] reads, per
// s: bf[4] reads + 16 MFMA} in one setprio cluster; barrier (protects
// buffer d from tile t+1's stage). Tail stages clamp to NT-1 -> dead buf.
// Per-acc order: t asc, h0{s0->M,s1->C}, h1{...} == R14 (bit-identical).
// ---------------------------------------------------------------------------
template<int HASC, int FMT>
__global__ __launch_bounds__(512) void gemm_mainL(
    const ushort* __restrict__ A,
    const ushort* __restrict__ Bh, const ushort* __restrict__ Bl,
    int NT, int K, int N,
    const ushort* __restrict__ curCin,
    const float* __restrict__ bias, ushort* __restrict__ spk)
{
  __shared__ __align__(16) ushort lds[67584];  // K-loop 128KB; epilogue [256][132] f32

  const int tid = threadIdx.x;
  const int lane = tid & 63;
  const int wid = tid >> 6;
  const int wm = wid >> 1;         // 0..3 (64-row strip)
  const int wn = wid & 1;          // 0..1 (64-col strip)
  const int lane15 = lane & 15;
  const int lhi = lane >> 4;
  const int sg2 = lhi ^ ((lane15 >> 1) & 3);

  int nwg = gridDim.x * gridDim.y;
  int bid = blockIdx.y * gridDim.x + blockIdx.x;
  int cpx = nwg >> 3;
  int sw = (bid & 7) * cpx + (bid >> 3);
  int bx = sw % gridDim.x, by = sw / gridDim.x;
  const int bm = by * 256, bn = bx * 128;

  const int sr2 = tid >> 2;
  const int sg = tid & 3;

  // full-tile stage: per half {2 A loads + 2 B loads} = 8 loads total
  auto stage = [&](int t1, int d) {
#pragma unroll
    for (int h = 0; h < 2; ++h) {
      const int k0 = t1 * 64 + h * 32;
#pragma unroll
      for (int l = 0; l < 2; ++l) {
        int row = sr2 + l * 128;
        __builtin_amdgcn_global_load_lds(
            (const __attribute__((address_space(1))) void*)(A + (size_t)(bm + row) * K + k0 + sg * 8),
            (__attribute__((address_space(3))) void*)(lds + d * 16384 + h * 8192 + row * 32 + sg * 8),
            16, 0, 0);
      }
#pragma unroll
      for (int s = 0; s < 2; ++s) {
        const ushort* Bp = (s == 0) ? Bh : Bl;
        __builtin_amdgcn_global_load_lds(
            (const __attribute__((address_space(1))) void*)(Bp + (size_t)(bn + sr2) * K + k0 + sg * 8),
            (__attribute__((address_space(3))) void*)(lds + 32768 + ((d * 2 + h) * 2 + s) * 4096 + sr2 * 32 + sg * 8),
            16, 0, 0);
      }
    }
  };

  f32x4 accM[4][4], accC[4][4];
#pragma unroll
  for (int i = 0; i < 4; ++i)
#pragma unroll
    for (int j = 0; j < 4; ++j) {
      accM[i][j] = (f32x4){0.f, 0.f, 0.f, 0.f};
      accC[i][j] = (f32x4){0.f, 0.f, 0.f, 0.f};
    }

  // prologue: tile 0 into buffer 0, fully drained
  stage(0, 0);
  asm volatile("s_waitcnt vmcnt(0)" ::: "memory");
  asm volatile("s_barrier" ::: "memory");

  for (int t = 0; t < NT; ++t) {
    const int d = t & 1;
    const int tn = (t + 1 < NT) ? t + 1 : NT - 1;   // tail dummy -> dead buf
    stage(tn, d ^ 1);
    asm volatile("s_waitcnt vmcnt(8)" ::: "memory");  // tile t landed (no-op at t=0)
    asm volatile("s_barrier" ::: "memory");

    __builtin_amdgcn_s_setprio(1);
#pragma unroll
    for (int h = 0; h < 2; ++h) {
      f16x8 af[4];
      const ushort* Ab = lds + (d * 2 + h) * 8192;
#pragma unroll
      for (int i = 0; i < 4; ++i)
        af[i] = *(const f16x8*)(Ab + (wm * 64 + i * 16 + lane15) * 32 + sg2 * 8);
#pragma unroll
      for (int s = 0; s < 2; ++s) {
        const ushort* Bb = lds + 32768 + ((d * 2 + h) * 2 + s) * 4096;
        f16x8 bf[4];
#pragma unroll
        for (int j = 0; j < 4; ++j)
          bf[j] = *(const f16x8*)(Bb + (wn * 64 + j * 16 + lane15) * 32 + sg2 * 8);
        if (s == 0) {
#pragma unroll
          for (int i = 0; i < 4; ++i)
#pragma unroll
            for (int j = 0; j < 4; ++j)
              accM[i][j] = __builtin_amdgcn_mfma_f32_16x16x32_f16(af[i], bf[j], accM[i][j], 0, 0, 0);
        } else {
#pragma unroll
          for (int i = 0; i < 4; ++i)
#pragma unroll
            for (int j = 0; j < 4; ++j)
              accC[i][j] = __builtin_amdgcn_mfma_f32_16x16x32_f16(af[i], bf[j], accC[i][j], 0, 0, 0);
        }
      }
    }
    __builtin_amdgcn_s_setprio(0);
    asm volatile("s_barrier" ::: "memory");  // buffer d free before next stage
  }

  // ---- fused LIF epilogue (verbatim R14) ----
  asm volatile("s_waitcnt vmcnt(0)" ::: "memory");
  __syncthreads();

  float* curb = (float*)lds;       // [256][132] f32 = 135168 B
#pragma unroll
  for (int i = 0; i < 4; ++i) {
    int rl = wm * 64 + i * 16 + lhi * 4;
#pragma unroll
    for (int j = 0; j < 4; ++j) {
      int cl = wn * 64 + j * 16 + lane15;
      f32x4 vm = accM[i][j], vc = accC[i][j];
#pragma unroll
      for (int r = 0; r < 4; ++r) {
        float corr = vc[r];
        if (HASC)
          corr += (float)u2h(curCin[(size_t)(bm + rl + r) * N + (bn + cl)]);
        curb[(rl + r) * 132 + cl] = __fmaf_rn(corr, 2.44140625e-4f, vm[r]);
      }
    }
  }
  __syncthreads();

  {
    int b2 = tid >> 7;           // 0..3 (batch within tile)
    int n = tid & 127;
    int cg = bn + n;
    float bv = bias[cg];
    int nb6 = cg >> 6;
    int sl = (cg >> 3) & 7;
    int nlow = cg & 7;
    const ushort one = FMT ? (ushort)0x3C00 : (ushort)0x3F80;
    float mem = 0.f;
    for (int t2 = 0; t2 < 64; ++t2) {
      float c = __fadd_rn(curb[(b2 * 64 + t2) * 132 + n], bv);
      float reset = ((mem - 1.0f) > 0.0f) ? 1.0f : 0.0f;
      mem = __fmul_rn(BETA, mem);
      mem = __fadd_rn(mem, c);
      mem = __fadd_rn(mem, -reset);
      ushort sv = ((mem - 1.0f) > 0.0f) ? one : (ushort)0;
      int m = bm + b2 * 64 + t2;
      int ps = FMT ? ((sl & 4) | ((sl & 3) ^ ((m >> 1) & 3)))
                   : (sl ^ (m & 7));
      spk[(size_t)m * N + (nb6 << 6) + (ps << 3) + nlow] = sv;
    }
  }
}

// ---------------------------------------------------------------------------
// gemm_seg_lif (L3): verbatim R14.
// ---------------------------------------------------------------------------
__global__ __launch_bounds__(256) void gemm_seg_lif(
    const ushort* __restrict__ A0,
    const ushort* __restrict__ B0, const ushort* __restrict__ B1,
    const ushort* __restrict__ B2,
    const float* __restrict__ bias,
    float* __restrict__ spk_out, float* __restrict__ mem_out)
{
  __shared__ ushort As[128 * 64];
  __shared__ ushort Bs[128 * 64];
  __shared__ float curb[128 * 132];

  const int tid = threadIdx.x;
  const int lane = tid & 63;
  const int wid = tid >> 6;
  const int wr = wid >> 1, wc = wid & 1;
  const int lane15 = lane & 15;
  const int lhi = lane >> 4;
  const int rswz = lane15 & 7;
  const int lrow = lane >> 3, lslot = lane & 7;

  int nwg = gridDim.x * gridDim.y;
  int bid = blockIdx.y * gridDim.x + blockIdx.x;
  int cpx = nwg >> 3;
  int sw = (bid & 7) * cpx + (bid >> 3);
  int bx = sw % gridDim.x, by = sw / gridDim.x;
  const int bm = by * 128, bn = bx * 128;

  f32x4 accM[4][4], accC[4][4];
#pragma unroll
  for (int i = 0; i < 4; ++i)
#pragma unroll
    for (int j = 0; j < 4; ++j) {
      accM[i][j] = (f32x4){0.f, 0.f, 0.f, 0.f};
      accC[i][j] = (f32x4){0.f, 0.f, 0.f, 0.f};
    }

  const bool isA = (wid < 2);
  ushort* lbase = isA ? As : Bs;
  const int rowbase0 = isA ? bm : bn;
  const int chunk0 = (wid & 1) * 8;

  for (int p = 0; p < 3; ++p) {
    const ushort* Bp = (p == 0) ? B0 : ((p == 1) ? B1 : B2);
    const ushort* gsrc = isA ? A0 : Bp;
    for (int k0 = 0; k0 < 1024; k0 += 64) {
      __syncthreads();
#pragma unroll
      for (int c = 0; c < 8; ++c) {
        int chunk = chunk0 + c;
        int row = chunk * 8 + lrow;
        const ushort* g = gsrc + (size_t)(rowbase0 + row) * 1024 + k0 + (lslot << 3);
        __builtin_amdgcn_global_load_lds(
            (const __attribute__((address_space(1))) void*)(g),
            (__attribute__((address_space(3))) void*)(lbase + chunk * 512),
            16, 0, 0);
      }
      __syncthreads();
#pragma unroll
      for (int kk = 0; kk < 2; ++kk) {
        int sp = ((kk << 2) | lhi) ^ rswz;
        bf16x8 af[4], bg[4];
#pragma unroll
        for (int i = 0; i < 4; ++i)
          af[i] = *(const bf16x8*)(As + (wr * 64 + i * 16 + lane15) * 64 + sp * 8);
#pragma unroll
        for (int j = 0; j < 4; ++j)
          bg[j] = *(const bf16x8*)(Bs + (wc * 64 + j * 16 + lane15) * 64 + sp * 8);
        if (p == 0) {
#pragma unroll
          for (int i = 0; i < 4; ++i)
#pragma unroll
            for (int j = 0; j < 4; ++j)
              accM[i][j] = __builtin_amdgcn_mfma_f32_16x16x32_bf16(af[i], bg[j], accM[i][j], 0, 0, 0);
        } else {
#pragma unroll
          for (int i = 0; i < 4; ++i)
#pragma unroll
            for (int j = 0; j < 4; ++j)
              accC[i][j] = __builtin_amdgcn_mfma_f32_16x16x32_bf16(af[i], bg[j], accC[i][j], 0, 0, 0);
        }
      }
    }
  }

  __syncthreads();
#pragma unroll
  for (int j = 0; j < 4; ++j) {
    int cl = wc * 64 + j * 16 + lane15;
#pragma unroll
    for (int i = 0; i < 4; ++i) {
      int rl = wr * 64 + i * 16 + lhi * 4;
      f32x4 vm = accM[i][j], vc = accC[i][j];
#pragma unroll
      for (int r = 0; r < 4; ++r)
        curb[(rl + r) * 132 + cl] = vm[r] + vc[r];
    }
  }
  __syncthreads();

  {
    int b2 = tid >> 7;
    int n = tid & 127;
    float bv = bias[bn + n];
    float mem = 0.f;
    for (int t2 = 0; t2 < 64; ++t2) {
      float c = __fadd_rn(curb[(b2 * 64 + t2) * 132 + n], bv);
      float reset = ((mem - 1.0f) > 0.0f) ? 1.0f : 0.0f;
      mem = __fmul_rn(BETA, mem);
      mem = __fadd_rn(mem, c);
      mem = __fadd_rn(mem, -reset);
      int m = bm + b2 * 64 + t2;
      size_t idx = (size_t)m * 128 + bn + n;
      spk_out[idx] = ((mem - 1.0f) > 0.0f) ? 1.0f : 0.0f;
      mem_out[idx] = mem;
    }
  }
}

extern "C" void kernel_launch(void* const* d_in, const int* in_sizes, int n_in,
                              void* d_out, int out_size, void* d_ws, size_t ws_size,
                              hipStream_t stream)
{
  const float* x  = (const float*)d_in[0];
  const float* W0 = (const float*)d_in[1];
  const float* b0 = (const float*)d_in[2];
  const float* W1 = (const float*)d_in[3];
  const float* b1 = (const float*)d_in[4];
  const float* W2 = (const float*)d_in[5];
  const float* b2 = (const float*)d_in[6];
  const float* W3 = (const float*)d_in[7];
  const float* b3 = (const float*)d_in[8];
  float* out = (float*)d_out;

  char* ws = (char*)d_ws;
  size_t off = 0;
  auto take = [&](size_t bytes) -> char* {
    char* p = ws + off;
    off += (bytes + 255) & ~(size_t)255;
    return p;
  };

  ushort* w0h = (ushort*)take((size_t)2048 * 2048 * 2);
  ushort* w0l = (ushort*)take((size_t)2048 * 2048 * 2);
  ushort* w1h = (ushort*)take((size_t)2048 * 2048 * 2);
  ushort* w1l = (ushort*)take((size_t)2048 * 2048 * 2);
  ushort* w2h = (ushort*)take((size_t)1024 * 2048 * 2);
  ushort* w2l = (ushort*)take((size_t)1024 * 2048 * 2);
  ushort* w3s[3];
  for (int i = 0; i < 3; ++i) w3s[i] = (ushort*)take((size_t)128 * 1024 * 2);
  ushort* xh = (ushort*)take((size_t)M_ * 2048 * 2);
  ushort* xl = (ushort*)take((size_t)M_ * 2048 * 2);
  ushort* s0 = (ushort*)take((size_t)M_ * 2048 * 2);
  ushort* curC = (ushort*)take((size_t)M_ * 2048 * 2);
  ushort* s1 = xh;
  ushort* s2 = xl;

  dim3 blk(256);
  dim3 fblk(512);

  // --- splits ---
  {
    int ns = 2048 * 2048 / 8;
    split2_f16<<<(ns + 255) / 256, blk, 0, stream>>>(W0, w0h, w0l, 2048, ns);
    split2_f16<<<(ns + 255) / 256, blk, 0, stream>>>(W1, w1h, w1l, 2048, ns);
    ns = 1024 * 2048 / 8;
    split2_f16<<<(ns + 255) / 256, blk, 0, stream>>>(W2, w2h, w2l, 2048, ns);
    ns = 128 * 1024 / 8;
    split3_swz<<<(ns + 255) / 256, blk, 0, stream>>>(W3, w3s[0], w3s[1], w3s[2], 1024, ns);
    ns = M_ * 2048 / 8;
    split2_f16<<<(ns + 255) / 256, blk, 0, stream>>>(x, xh, xl, 2048, ns);
  }

  // --- L0: corr first (xl*wh -> curC), then main + LIF -> s0 ---
  {
    dim3 grid(2048 / 128, M_ / 256);   // (16, 32)
    gemm_corr<<<grid, fblk, 0, stream>>>(xl, w0h, 32, 2048, 2048, curC);
    gemm_mainL<1, 1><<<grid, fblk, 0, stream>>>(xh, w0h, w0l, 32, 2048, 2048, curC, b0, s0);
  }
  // --- L1 ---
  {
    dim3 grid(2048 / 128, M_ / 256);
    gemm_mainL<0, 1><<<grid, fblk, 0, stream>>>(s0, w1h, w1l, 32, 2048, 2048, nullptr, b1, s1);
  }
  // --- L2 (spikes out bf16 mode-0 for L3) ---
  {
    dim3 grid(1024 / 128, M_ / 256);   // (8, 32)
    gemm_mainL<0, 0><<<grid, fblk, 0, stream>>>(s1, w2h, w2l, 32, 2048, 1024, nullptr, b2, s2);
  }
  // --- L3: single fused kernel -> spk3, mem3 ---
  {
    float* spk3 = out;
    float* mem3 = out + (size_t)M_ * NOUT;
    gemm_seg_lif<<<dim3(1, 64), blk, 0, stream>>>(s2, w3s[0], w3s[1], w3s[2], b3, spk3, mem3);
  }
}

// Round 17
// 477.363 us; speedup vs baseline: 1.1224x; 1.1224x over previous
//
#include <hip/hip_runtime.h>
#include <cstddef>
#include <cstdint>

// SNN: 4x (Linear + LIF). fp16 2-term exact splitting + fused in-LDS LIF.
// R17 = R14 (proven 478.8us, absmax 0.0) with gemm_corr FOLDED into the L0
// main launch as pass 1 (A=xl, B=wh -> accC; dummy seg-1 staging keeps the
// per-phase 4-load vmcnt(4) ledger identical to R14). No curC buffer.
// L1/L2 instantiate NP=1 (identical to R14 behavior). Loop schedule,
// epilogues, splits, seg_lif: verbatim R14.

#define BETA 0.95f

static constexpr int B_ = 128;
static constexpr int T_ = 64;
static constexpr int M_ = B_ * T_;       // 8192 rows
static constexpr int NOUT = 128;

typedef __bf16 bf16x8 __attribute__((ext_vector_type(8)));
typedef _Float16 f16x8 __attribute__((ext_vector_type(8)));
typedef float f32x4 __attribute__((ext_vector_type(4)));
typedef ushort u16x8 __attribute__((ext_vector_type(8)));

__device__ __forceinline__ ushort f32_bf16_rne(float f) {
  uint32_t u = __float_as_uint(f);
  uint32_t r = u + 0x7FFFu + ((u >> 16) & 1u);
  return (ushort)(r >> 16);
}
__device__ __forceinline__ float bf16_f32(ushort h) {
  return __uint_as_float(((uint32_t)h) << 16);
}
__device__ __forceinline__ ushort h2u(_Float16 h) {
  union { _Float16 h; ushort u; } v; v.h = h; return v.u;
}
__device__ __forceinline__ _Float16 u2h(ushort u) {
  union { ushort u; _Float16 h; } v; v.u = u; return v.h;
}

// ---------------------------------------------------------------------------
// fp32 -> 2 fp16 exact split (h + 2^-12 * l'), mode-1 swizzled positions.
// Subnormal-safe: |h|<2^-14 zeroed; value flows through l'.
// ---------------------------------------------------------------------------
__global__ __launch_bounds__(256) void split2_f16(
    const float* __restrict__ S, ushort* __restrict__ oh,
    ushort* __restrict__ ol, int K, int nslots)
{
  int g = blockIdx.x * 256 + threadIdx.x;
  if (g >= nslots) return;
  int spr = K >> 3;
  int row = g / spr;
  int sl = g - row * spr;
  int kb = sl >> 3;
  int slot = sl & 7;
  int pslot = (slot & 4) | ((slot & 3) ^ ((row >> 1) & 3));
  const float* src = S + (size_t)row * K + (kb << 6) + (slot << 3);
  size_t dst = (size_t)row * K + (kb << 6) + (pslot << 3);
  u16x8 vh, vl;
#pragma unroll
  for (int i = 0; i < 8; ++i) {
    float f = src[i];
    _Float16 h = (_Float16)f;
    float hf = (float)h;
    if (fabsf(hf) < 6.103515625e-05f) { h = (_Float16)0.0f; hf = 0.0f; }
    float l = (f - hf) * 4096.0f;
    vh[i] = h2u(h);
    vl[i] = h2u((_Float16)l);
  }
  *reinterpret_cast<u16x8*>(oh + dst) = vh;
  *reinterpret_cast<u16x8*>(ol + dst) = vl;
}

// ---------------------------------------------------------------------------
// fp32 -> 3 bf16 exact split, mode-0 swizzle (L3 operands only).
// ---------------------------------------------------------------------------
__global__ __launch_bounds__(256) void split3_swz(
    const float* __restrict__ S, ushort* __restrict__ o1,
    ushort* __restrict__ o2, ushort* __restrict__ o3,
    int K, int nslots)
{
  int g = blockIdx.x * 256 + threadIdx.x;
  if (g >= nslots) return;
  int spr = K >> 3;
  int row = g / spr;
  int sl = g - row * spr;
  int kb = sl >> 3;
  int slot = sl & 7;
  int pslot = slot ^ (row & 7);
  const float* src = S + (size_t)row * K + (kb << 6) + (slot << 3);
  size_t dst = (size_t)row * K + (kb << 6) + (pslot << 3);
  u16x8 v1, v2, v3;
#pragma unroll
  for (int i = 0; i < 8; ++i) {
    float f = src[i];
    ushort h1 = f32_bf16_rne(f);
    float r = f - bf16_f32(h1);
    ushort h2 = f32_bf16_rne(r);
    float r2 = r - bf16_f32(h2);
    ushort h3 = f32_bf16_rne(r2);
    v1[i] = h1; v2[i] = h2; v3[i] = h3;
  }
  *reinterpret_cast<u16x8*>(o1 + dst) = v1;
  *reinterpret_cast<u16x8*>(o2 + dst) = v2;
  *reinterpret_cast<u16x8*>(o3 + dst) = v3;
}

// ---------------------------------------------------------------------------
// gemm_mainL<NP, FMT>: R14's proven 2-phase loop, extended to NP passes.
// Pass p reads A_p; B segs {Bh_p -> accM (p==0 only), Bl_p -> accC}.
// Pass 1 (L0 corr, A=xl): nb=1, seg0 -> accC; seg1 staging is a dummy
// (Bl_1 = wh) so the per-phase ledger (4 loads, vmcnt(4)) is IDENTICAL
// to R14's. NT = NP*32 K-tiles; stage pointers derive from the staged
// tile's pass. Fused LIF epilogue (verbatim R14, no curC read).
// LDS: A [2 dbuf][2 half][256][32] f16 (64KB) + B [2 dbuf][2 half][2 seg]
// [128][32] (64KB); epilogue reuses as [256][132] f32.
// ---------------------------------------------------------------------------
template<int NP, int FMT>
__global__ __launch_bounds__(512) void gemm_mainL(
    const ushort* __restrict__ A0p, const ushort* __restrict__ A1p,
    const ushort* __restrict__ Bh0, const ushort* __restrict__ Bl0,
    const ushort* __restrict__ Bh1, const ushort* __restrict__ Bl1,
    int K, int N,
    const float* __restrict__ bias, ushort* __restrict__ spk)
{
  __shared__ __align__(16) ushort lds[67584];  // K-loop 128KB; epilogue [256][132] f32

  const int tid = threadIdx.x;
  const int lane = tid & 63;
  const int wid = tid >> 6;
  const int wm = wid >> 1;         // 0..3 (64-row strip)
  const int wn = wid & 1;          // 0..1 (64-col strip)
  const int lane15 = lane & 15;
  const int lhi = lane >> 4;
  const int sg2 = lhi ^ ((lane15 >> 1) & 3);

  int nwg = gridDim.x * gridDim.y;
  int bid = blockIdx.y * gridDim.x + blockIdx.x;
  int cpx = nwg >> 3;
  int sw = (bid & 7) * cpx + (bid >> 3);
  int bx = sw % gridDim.x, by = sw / gridDim.x;
  const int bm = by * 256, bn = bx * 128;

  const int sr2 = tid >> 2;
  const int sg = tid & 3;

  const ushort* Aps[2] = {A0p, (NP == 2) ? A1p : A0p};
  const ushort* Bhs[2] = {Bh0, (NP == 2) ? Bh1 : Bh0};
  const ushort* Bls[2] = {Bl0, (NP == 2) ? Bl1 : Bl0};

  // stage half h of K-tile t1 into dbuf d: 2 A loads + 2 B loads (1/seg)
  auto stage = [&](int t1, int h, int d) {
    const int pn = t1 >> 5;
    const int k0 = (t1 & 31) * 64 + h * 32;
    const ushort* Ap = Aps[pn];
#pragma unroll
    for (int l = 0; l < 2; ++l) {
      int row = sr2 + l * 128;
      __builtin_amdgcn_global_load_lds(
          (const __attribute__((address_space(1))) void*)(Ap + (size_t)(bm + row) * K + k0 + sg * 8),
          (__attribute__((address_space(3))) void*)(lds + d * 16384 + h * 8192 + row * 32 + sg * 8),
          16, 0, 0);
    }
#pragma unroll
    for (int s = 0; s < 2; ++s) {
      const ushort* Bp = (s == 0) ? Bhs[pn] : Bls[pn];
      __builtin_amdgcn_global_load_lds(
          (const __attribute__((address_space(1))) void*)(Bp + (size_t)(bn + sr2) * K + k0 + sg * 8),
          (__attribute__((address_space(3))) void*)(lds + 32768 + ((d * 2 + h) * 2 + s) * 4096 + sr2 * 32 + sg * 8),
          16, 0, 0);
    }
  };

  f32x4 accM[4][4], accC[4][4];
#pragma unroll
  for (int i = 0; i < 4; ++i)
#pragma unroll
    for (int j = 0; j < 4; ++j) {
      accM[i][j] = (f32x4){0.f, 0.f, 0.f, 0.f};
      accC[i][j] = (f32x4){0.f, 0.f, 0.f, 0.f};
    }

  const int NT = NP * 32;

  // prologue: stage tile 0 halves into dbuf 0; drain fully (R14)
  stage(0, 0, 0);
  stage(0, 1, 0);
  asm volatile("s_waitcnt vmcnt(0)" ::: "memory");
  asm volatile("s_barrier" ::: "memory");

  for (int t = 0; t < NT; ++t) {
    const int d = t & 1;
    const int p = t >> 5;
    const int nb = (NP == 2 && p == 1) ? 1 : 2;
#pragma unroll
    for (int h = 0; h < 2; ++h) {
      f16x8 af[4];
      const ushort* Ab = lds + (d * 2 + h) * 8192;
#pragma unroll
      for (int i = 0; i < 4; ++i)
        af[i] = *(const f16x8*)(Ab + (wm * 64 + i * 16 + lane15) * 32 + sg2 * 8);

      if (t < NT - 1) {
        stage(t + 1, h, d ^ 1);
        asm volatile("s_waitcnt vmcnt(4)" ::: "memory");
      } else if (h == 0) {
        asm volatile("s_waitcnt vmcnt(0)" ::: "memory");
      }
      asm volatile("s_barrier" ::: "memory");

      __builtin_amdgcn_s_setprio(1);
#pragma unroll
      for (int s = 0; s < 2; ++s) {
        if (s < nb) {
          const ushort* Bb = lds + 32768 + ((d * 2 + h) * 2 + s) * 4096;
          f16x8 bf[4];
#pragma unroll
          for (int j = 0; j < 4; ++j)
            bf[j] = *(const f16x8*)(Bb + (wn * 64 + j * 16 + lane15) * 32 + sg2 * 8);
          if (p == 0 && s == 0) {
#pragma unroll
            for (int i = 0; i < 4; ++i)
#pragma unroll
              for (int j = 0; j < 4; ++j)
                accM[i][j] = __builtin_amdgcn_mfma_f32_16x16x32_f16(af[i], bf[j], accM[i][j], 0, 0, 0);
          } else {
#pragma unroll
            for (int i = 0; i < 4; ++i)
#pragma unroll
              for (int j = 0; j < 4; ++j)
                accC[i][j] = __builtin_amdgcn_mfma_f32_16x16x32_f16(af[i], bf[j], accC[i][j], 0, 0, 0);
          }
        }
      }
      __builtin_amdgcn_s_setprio(0);
      asm volatile("s_barrier" ::: "memory");
    }
  }

  // ---- fused LIF epilogue (verbatim R14, no curC read) ----
  asm volatile("s_waitcnt vmcnt(0)" ::: "memory");
  __syncthreads();

  float* curb = (float*)lds;       // [256][132] f32 = 135168 B
#pragma unroll
  for (int i = 0; i < 4; ++i) {
    int rl = wm * 64 + i * 16 + lhi * 4;
#pragma unroll
    for (int j = 0; j < 4; ++j) {
      int cl = wn * 64 + j * 16 + lane15;
      f32x4 vm = accM[i][j], vc = accC[i][j];
#pragma unroll
      for (int r = 0; r < 4; ++r)
        curb[(rl + r) * 132 + cl] = __fmaf_rn(vc[r], 2.44140625e-4f, vm[r]);
    }
  }
  __syncthreads();

  {
    int b2 = tid >> 7;           // 0..3 (batch within tile)
    int n = tid & 127;
    int cg = bn + n;
    float bv = bias[cg];
    int nb6 = cg >> 6;
    int sl = (cg >> 3) & 7;
    int nlow = cg & 7;
    const ushort one = FMT ? (ushort)0x3C00 : (ushort)0x3F80;
    float mem = 0.f;
    for (int t2 = 0; t2 < 64; ++t2) {
      float c = __fadd_rn(curb[(b2 * 64 + t2) * 132 + n], bv);
      float reset = ((mem - 1.0f) > 0.0f) ? 1.0f : 0.0f;
      mem = __fmul_rn(BETA, mem);
      mem = __fadd_rn(mem, c);
      mem = __fadd_rn(mem, -reset);
      ushort sv = ((mem - 1.0f) > 0.0f) ? one : (ushort)0;
      int m = bm + b2 * 64 + t2;
      int ps = FMT ? ((sl & 4) | ((sl & 3) ^ ((m >> 1) & 3)))
                   : (sl ^ (m & 7));
      spk[(size_t)m * N + (nb6 << 6) + (ps << 3) + nlow] = sv;
    }
  }
}

// ---------------------------------------------------------------------------
// gemm_seg_lif (L3): verbatim R14.
// ---------------------------------------------------------------------------
__global__ __launch_bounds__(256) void gemm_seg_lif(
    const ushort* __restrict__ A0,
    const ushort* __restrict__ B0, const ushort* __restrict__ B1,
    const ushort* __restrict__ B2,
    const float* __restrict__ bias,
    float* __restrict__ spk_out, float* __restrict__ mem_out)
{
  __shared__ ushort As[128 * 64];
  __shared__ ushort Bs[128 * 64];
  __shared__ float curb[128 * 132];

  const int tid = threadIdx.x;
  const int lane = tid & 63;
  const int wid = tid >> 6;
  const int wr = wid >> 1, wc = wid & 1;
  const int lane15 = lane & 15;
  const int lhi = lane >> 4;
  const int rswz = lane15 & 7;
  const int lrow = lane >> 3, lslot = lane & 7;

  int nwg = gridDim.x * gridDim.y;
  int bid = blockIdx.y * gridDim.x + blockIdx.x;
  int cpx = nwg >> 3;
  int sw = (bid & 7) * cpx + (bid >> 3);
  int bx = sw % gridDim.x, by = sw / gridDim.x;
  const int bm = by * 128, bn = bx * 128;

  f32x4 accM[4][4], accC[4][4];
#pragma unroll
  for (int i = 0; i < 4; ++i)
#pragma unroll
    for (int j = 0; j < 4; ++j) {
      accM[i][j] = (f32x4){0.f, 0.f, 0.f, 0.f};
      accC[i][j] = (f32x4){0.f, 0.f, 0.f, 0.f};
    }

  const bool isA = (wid < 2);
  ushort* lbase = isA ? As : Bs;
  const int rowbase0 = isA ? bm : bn;
  const int chunk0 = (wid & 1) * 8;

  for (int p = 0; p < 3; ++p) {
    const ushort* Bp = (p == 0) ? B0 : ((p == 1) ? B1 : B2);
    const ushort* gsrc = isA ? A0 : Bp;
    for (int k0 = 0; k0 < 1024; k0 += 64) {
      __syncthreads();
#pragma unroll
      for (int c = 0; c < 8; ++c) {
        int chunk = chunk0 + c;
        int row = chunk * 8 + lrow;
        const ushort* g = gsrc + (size_t)(rowbase0 + row) * 1024 + k0 + (lslot << 3);
        __builtin_amdgcn_global_load_lds(
            (const __attribute__((address_space(1))) void*)(g),
            (__attribute__((address_space(3))) void*)(lbase + chunk * 512),
            16, 0, 0);
      }
      __syncthreads();
#pragma unroll
      for (int kk = 0; kk < 2; ++kk) {
        int sp = ((kk << 2) | lhi) ^ rswz;
        bf16x8 af[4], bg[4];
#pragma unroll
        for (int i = 0; i < 4; ++i)
          af[i] = *(const bf16x8*)(As + (wr * 64 + i * 16 + lane15) * 64 + sp * 8);
#pragma unroll
        for (int j = 0; j < 4; ++j)
          bg[j] = *(const bf16x8*)(Bs + (wc * 64 + j * 16 + lane15) * 64 + sp * 8);
        if (p == 0) {
#pragma unroll
          for (int i = 0; i < 4; ++i)
#pragma unroll
            for (int j = 0; j < 4; ++j)
              accM[i][j] = __builtin_amdgcn_mfma_f32_16x16x32_bf16(af[i], bg[j], accM[i][j], 0, 0, 0);
        } else {
#pragma unroll
          for (int i = 0; i < 4; ++i)
#pragma unroll
            for (int j = 0; j < 4; ++j)
              accC[i][j] = __builtin_amdgcn_mfma_f32_16x16x32_bf16(af[i], bg[j], accC[i][j], 0, 0, 0);
        }
      }
    }
  }

  __syncthreads();
#pragma unroll
  for (int j = 0; j < 4; ++j) {
    int cl = wc * 64 + j * 16 + lane15;
#pragma unroll
    for (int i = 0; i < 4; ++i) {
      int rl = wr * 64 + i * 16 + lhi * 4;
      f32x4 vm = accM[i][j], vc = accC[i][j];
#pragma unroll
      for (int r = 0; r < 4; ++r)
        curb[(rl + r) * 132 + cl] = vm[r] + vc[r];
    }
  }
  __syncthreads();

  {
    int b2 = tid >> 7;
    int n = tid & 127;
    float bv = bias[bn + n];
    float mem = 0.f;
    for (int t2 = 0; t2 < 64; ++t2) {
      float c = __fadd_rn(curb[(b2 * 64 + t2) * 132 + n], bv);
      float reset = ((mem - 1.0f) > 0.0f) ? 1.0f : 0.0f;
      mem = __fmul_rn(BETA, mem);
      mem = __fadd_rn(mem, c);
      mem = __fadd_rn(mem, -reset);
      int m = bm + b2 * 64 + t2;
      size_t idx = (size_t)m * 128 + bn + n;
      spk_out[idx] = ((mem - 1.0f) > 0.0f) ? 1.0f : 0.0f;
      mem_out[idx] = mem;
    }
  }
}

extern "C" void kernel_launch(void* const* d_in, const int* in_sizes, int n_in,
                              void* d_out, int out_size, void* d_ws, size_t ws_size,
                              hipStream_t stream)
{
  const float* x  = (const float*)d_in[0];
  const float* W0 = (const float*)d_in[1];
  const float* b0 = (const float*)d_in[2];
  const float* W1 = (const float*)d_in[3];
  const float* b1 = (const float*)d_in[4];
  const float* W2 = (const float*)d_in[5];
  const float* b2 = (const float*)d_in[6];
  const float* W3 = (const float*)d_in[7];
  const float* b3 = (const float*)d_in[8];
  float* out = (float*)d_out;

  char* ws = (char*)d_ws;
  size_t off = 0;
  auto take = [&](size_t bytes) -> char* {
    char* p = ws + off;
    off += (bytes + 255) & ~(size_t)255;
    return p;
  };

  ushort* w0h = (ushort*)take((size_t)2048 * 2048 * 2);
  ushort* w0l = (ushort*)take((size_t)2048 * 2048 * 2);
  ushort* w1h = (ushort*)take((size_t)2048 * 2048 * 2);
  ushort* w1l = (ushort*)take((size_t)2048 * 2048 * 2);
  ushort* w2h = (ushort*)take((size_t)1024 * 2048 * 2);
  ushort* w2l = (ushort*)take((size_t)1024 * 2048 * 2);
  ushort* w3s[3];
  for (int i = 0; i < 3; ++i) w3s[i] = (ushort*)take((size_t)128 * 1024 * 2);
  ushort* xh = (ushort*)take((size_t)M_ * 2048 * 2);
  ushort* xl = (ushort*)take((size_t)M_ * 2048 * 2);
  ushort* s0 = (ushort*)take((size_t)M_ * 2048 * 2);
  // s1 aliases xh (dead after L0), s2 aliases xl (dead after L0's pass 1)
  ushort* s1 = xh;
  ushort* s2 = xl;

  dim3 blk(256);
  dim3 fblk(512);

  // --- splits ---
  {
    int ns = 2048 * 2048 / 8;
    split2_f16<<<(ns + 255) / 256, blk, 0, stream>>>(W0, w0h, w0l, 2048, ns);
    split2_f16<<<(ns + 255) / 256, blk, 0, stream>>>(W1, w1h, w1l, 2048, ns);
    ns = 1024 * 2048 / 8;
    split2_f16<<<(ns + 255) / 256, blk, 0, stream>>>(W2, w2h, w2l, 2048, ns);
    ns = 128 * 1024 / 8;
    split3_swz<<<(ns + 255) / 256, blk, 0, stream>>>(W3, w3s[0], w3s[1], w3s[2], 1024, ns);
    ns = M_ * 2048 / 8;
    split2_f16<<<(ns + 255) / 256, blk, 0, stream>>>(x, xh, xl, 2048, ns);
  }

  // --- L0: single launch, 2 passes (xh*{wh,wl}; xl*{wh}) + LIF -> s0 ---
  {
    dim3 grid(2048 / 128, M_ / 256);   // (16, 32)
    gemm_mainL<2, 1><<<grid, fblk, 0, stream>>>(
        xh, xl, w0h, w0l, w0h, w0h, 2048, 2048, b0, s0);
  }
  // --- L1 ---
  {
    dim3 grid(2048 / 128, M_ / 256);
    gemm_mainL<1, 1><<<grid, fblk, 0, stream>>>(
        s0, s0, w1h, w1l, w1h, w1l, 2048, 2048, b1, s1);
  }
  // --- L2 (spikes out bf16 mode-0 for L3) ---
  {
    dim3 grid(1024 / 128, M_ / 256);   // (8, 32)
    gemm_mainL<1, 0><<<grid, fblk, 0, stream>>>(
        s1, s1, w2h, w2l, w2h, w2l, 2048, 1024, b2, s2);
  }
  // --- L3: single fused kernel -> spk3, mem3 ---
  {
    float* spk3 = out;
    float* mem3 = out + (size_t)M_ * NOUT;
    gemm_seg_lif<<<dim3(1, 64), blk, 0, stream>>>(s2, w3s[0], w3s[1], w3s[2], b3, spk3, mem3);
  }
}